// Round 9
// baseline (129.358 us; speedup 1.0000x reference)
//
#include <hip/hip_runtime.h>

#define B_TOT    4096
#define NSTEPS   4
#define E        128
#define OUT_DIM  16
#define NMOD     64
#define KSPLIT   4
#define TILE     16
#define GRID     256
#define SENT     0x13579BDF

// ws int offsets:
#define SORTF_I    0                          // [4] sort-done sentinels
#define FLAG_I(s)  (64 + ((s) - 1) * B_TOT)   // s=1..3: row flags for XB_{s-1}
#define CNT_I      12352                      // [4][64]
#define OFF_I      (CNT_I + 256)              // [4][64]
#define PERM_I     (CNT_I + 512)              // [4][4096]
#define RANK_I     (PERM_I + 4 * B_TOT)       // [4][4096]
#define PERMA0_I   (RANK_I + 4 * B_TOT)       // [4096]
#define XB_BYTE(i) ((size_t)(1 + (i)) << 20)  // XB0/1/2: [4096][128] f16, 1 MB each

typedef _Float16 f16;
using f16x8 = __attribute__((ext_vector_type(8))) f16;
using f32x4 = __attribute__((ext_vector_type(4))) float;
union HU  { f16 h; unsigned short u; };
union U4H { uint4 u4; f16x8 h8; };

#define AGENT __HIP_MEMORY_SCOPE_AGENT

__device__ __forceinline__ float tanh_fast(float x) {
    return 1.0f - 2.0f / (__expf(2.0f * x) + 1.0f);
}
__device__ __forceinline__ unsigned short f2h(float x) { HU v; v.h = (f16)x; return v.u; }
__device__ __forceinline__ void s_store(int* p, int v) {
    __hip_atomic_store(p, v, __ATOMIC_RELAXED, AGENT);
}
__device__ __forceinline__ void h_store(unsigned short* p, unsigned short v) {
    __hip_atomic_store(p, v, __ATOMIC_RELAXED, AGENT);
}

__global__ __launch_bounds__(256) void fused_kernel(
    const int* __restrict__ mids,
    const int* __restrict__ author_ids,
    const float* __restrict__ embed,
    const float* __restrict__ W,
    const float* __restrict__ bias,
    const float* __restrict__ cls_W,
    const float* __restrict__ cls_b,
    float* __restrict__ out,
    int* __restrict__ ws)
{
    const int bid = blockIdx.x;
    const int t   = threadIdx.x;
    const int w   = t >> 6;
    const int l   = t & 63;

    __shared__ int            s_hist[NMOD * NMOD];   // [chunk][m], 16 KB
    __shared__ unsigned char  s_wr[B_TOT];
    __shared__ unsigned char  s_mm[B_TOT];
    __shared__ int            s_off[NMOD];
    __shared__ __align__(16) float Yl[TILE * (E + 4)];

    // ================= blocks 0..3: deterministic stable counting sort =================
    if (bid < NSTEPS) {
        const int s = bid;
        // phase 1: per-chunk (64 elems) within-chunk stable ranks + histograms
        for (int i = 0; i < 16; ++i) {
            const int c = (w << 4) + i;
            const int b = (c << 6) + l;
            const int m = mids[b * NSTEPS + s];
            unsigned wr_ = 0;
            for (int v = 0; v < NMOD; ++v) {
                const unsigned long long mask = __ballot(m == v);
                if (m == v) wr_ = (unsigned)__popcll(mask & ((1ull << l) - 1));
                if (l == v) s_hist[c * NMOD + v] = (int)__popcll(mask);
            }
            s_wr[b] = (unsigned char)wr_;
            s_mm[b] = (unsigned char)m;
        }
        __syncthreads();
        // phase 2: serial chunk-scan per m (thread t<64 owns module t), then off scan
        if (t < NMOD) {
            int run = 0;
            for (int c = 0; c < NMOD; ++c) {
                const int v = s_hist[c * NMOD + t];
                s_hist[c * NMOD + t] = run;
                run += v;
            }
            const int tot = run;
            int inc = tot;
            #pragma unroll
            for (int d = 1; d < NMOD; d <<= 1) {
                const int nv = __shfl_up(inc, d, 64);
                if (t >= d) inc += nv;
            }
            const int off = inc - tot;
            s_off[t] = off;
            s_store(&ws[CNT_I + s * NMOD + t], tot);
            s_store(&ws[OFF_I + s * NMOD + t], off);
        }
        __syncthreads();
        // phase 3: scatter (all ranks deterministic)
        int* __restrict__ perm = ws + PERM_I + s * B_TOT;
        int* __restrict__ rank = ws + RANK_I + s * B_TOT;
        for (int b = t; b < B_TOT; b += 256) {
            const int m  = s_mm[b];
            const int rk = s_off[m] + s_hist[(b >> 6) * NMOD + m] + s_wr[b];
            s_store(&rank[b], rk);
            s_store(&perm[rk], b);
            if (s == 0) s_store(&ws[PERMA0_I + rk], author_ids[b]);
        }
        __syncthreads();                                  // all waves' stores drained
        __builtin_amdgcn_fence(__ATOMIC_RELEASE, "agent");
        if (t == 0) s_store(&ws[SORTF_I + s], SENT);
    }

    // ================= all 256 blocks: compute =================
    const int m  = bid & (NMOD - 1);        // all 4 slices of module m on XCD m%8
    const int k  = bid >> 6;                // slice 0..3
    const int g  = l >> 4;
    const int r0 = l & 15;
    const int c0 = 32 * w + r0;
    const int c1 = c0 + 16;

    // ---- module W -> f16 hi/lo fragments in registers ----
    f16x8 BH0[4], BL0[4], BH1[4], BL1[4];
    {
        const float* __restrict__ wb = W + (size_t)m * E * E;
        #pragma unroll
        for (int ss = 0; ss < 4; ++ss) {
            const f32x4* __restrict__ p0 = (const f32x4*)(wb + c0 * E + ss * 32 + g * 8);
            const f32x4* __restrict__ p1 = (const f32x4*)(wb + c1 * E + ss * 32 + g * 8);
            const f32x4 a0 = p0[0], a1 = p0[1];
            const f32x4 d0 = p1[0], d1 = p1[1];
            const float x0[8] = {a0.x, a0.y, a0.z, a0.w, a1.x, a1.y, a1.z, a1.w};
            const float x1[8] = {d0.x, d0.y, d0.z, d0.w, d1.x, d1.y, d1.z, d1.w};
            #pragma unroll
            for (int j = 0; j < 8; ++j) {
                const f16 h0 = (f16)x0[j];
                const f16 h1 = (f16)x1[j];
                BH0[ss][j] = h0;  BL0[ss][j] = (f16)(x0[j] - (float)h0);
                BH1[ss][j] = h1;  BL1[ss][j] = (f16)(x1[j] - (float)h1);
            }
        }
    }
    const float b0 = bias[m * E + c0];
    const float b1 = bias[m * E + c1];

    // ---- wait for all 4 sorts (sentinel; stale SENT is harmless: contents replay-invariant) ----
    if (t < NSTEPS)
        while (__hip_atomic_load(&ws[SORTF_I + t], __ATOMIC_RELAXED, AGENT) != SENT)
            __builtin_amdgcn_s_sleep(8);
    __syncthreads();
    __builtin_amdgcn_fence(__ATOMIC_ACQUIRE, "agent");

    for (int s = 0; s < NSTEPS; ++s) {
        const int cnt = ws[CNT_I + s * NMOD + m];
        const int off = ws[OFF_I + s * NMOD + m];
        const int end = off + cnt;
        const int* __restrict__ permS = ws + PERM_I + s * B_TOT;
        const int* __restrict__ rankN = ws + RANK_I + ((s + 1) & 3) * B_TOT;   // used only s<3
        const int* __restrict__ flagIn  = (s > 0) ? ws + FLAG_I(s)     : nullptr;
        int*       __restrict__ flagOut = (s < 3) ? ws + FLAG_I(s + 1) : nullptr;
        const f16* __restrict__ xbIn  = (s > 0) ? (const f16*)((char*)ws + XB_BYTE(s - 1)) : nullptr;
        f16*       __restrict__ xbOut = (s < 3) ? (f16*)((char*)ws + XB_BYTE(s))           : nullptr;

        for (int base = off + k * TILE; base < end; base += KSPLIT * TILE) {
            const int nb   = min(TILE, end - base);
            const bool rok = r0 < nb;
            const int rr   = base + (rok ? r0 : 0);

            // ---- wait for this tile's input rows ----
            if (s > 0) {
                if (rok)
                    while (__hip_atomic_load(&flagIn[rr], __ATOMIC_RELAXED, AGENT) != SENT)
                        __builtin_amdgcn_s_sleep(1);
                __builtin_amdgcn_fence(__ATOMIC_ACQUIRE, "agent");
            }

            const int ob   = permS[rr];
            const int dmap = (s < 3) ? rankN[ob] : ob;

            // ---- A fragments (row r0) ----
            f16x8 A[4];
            if (s == 0) {
                const f32x4* __restrict__ src =
                    (const f32x4*)(embed + (size_t)ws[PERMA0_I + rr] * E);
                #pragma unroll
                for (int ss = 0; ss < 4; ++ss) {
                    if (rok) {
                        const f32x4 v0 = src[ss * 8 + 2 * g];
                        const f32x4 v1 = src[ss * 8 + 2 * g + 1];
                        const float xf[8] = {v0.x, v0.y, v0.z, v0.w, v1.x, v1.y, v1.z, v1.w};
                        #pragma unroll
                        for (int j = 0; j < 8; ++j) A[ss][j] = (f16)xf[j];
                    } else {
                        #pragma unroll
                        for (int j = 0; j < 8; ++j) A[ss][j] = (f16)0.0f;
                    }
                }
            } else {
                const uint4* __restrict__ src = (const uint4*)(xbIn + (size_t)rr * E);
                #pragma unroll
                for (int ss = 0; ss < 4; ++ss) {
                    if (rok) {
                        U4H u; u.u4 = src[ss * 4 + g];
                        A[ss] = u.h8;
                    } else {
                        #pragma unroll
                        for (int j = 0; j < 8; ++j) A[ss][j] = (f16)0.0f;
                    }
                }
            }

            // ---- 16 MFMAs: acc = A * (Whi + Wlo) ----
            f32x4 acc0 = {0.f, 0.f, 0.f, 0.f};
            f32x4 acc1 = {0.f, 0.f, 0.f, 0.f};
            #pragma unroll
            for (int ss = 0; ss < 4; ++ss) {
                acc0 = __builtin_amdgcn_mfma_f32_16x16x32_f16(A[ss], BH0[ss], acc0, 0, 0, 0);
                acc1 = __builtin_amdgcn_mfma_f32_16x16x32_f16(A[ss], BH1[ss], acc1, 0, 0, 0);
                acc0 = __builtin_amdgcn_mfma_f32_16x16x32_f16(A[ss], BL0[ss], acc0, 0, 0, 0);
                acc1 = __builtin_amdgcn_mfma_f32_16x16x32_f16(A[ss], BL1[ss], acc1, 0, 0, 0);
            }

            // ---- epilogue: D row = 4g + r, cols c0/c1 ----
            if (s < 3) {
                #pragma unroll
                for (int r = 0; r < 4; ++r) {
                    const int row = 4 * g + r;
                    const int dr  = __shfl(dmap, row, 16);
                    if (row < nb) {
                        f16* __restrict__ dst = xbOut + (size_t)dr * E;
                        h_store((unsigned short*)&dst[c0], f2h(tanh_fast(acc0[r] + b0)));
                        h_store((unsigned short*)&dst[c1], f2h(tanh_fast(acc1[r] + b1)));
                    }
                }
                __syncthreads();                                  // all waves' data stores drained
                __builtin_amdgcn_fence(__ATOMIC_RELEASE, "agent");
                if (t < 16 && t < nb)                             // lane t holds dmap for row t
                    s_store(&flagOut[dmap], SENT);
            } else {
                #pragma unroll
                for (int r = 0; r < 4; ++r) {
                    const int row = 4 * g + r;
                    Yl[row * (E + 4) + c0] = acc0[r] + b0;
                    Yl[row * (E + 4) + c1] = acc1[r] + b1;
                }
                __syncthreads();
                const int row  = t >> 4, j = t & 15;
                const int outb = __shfl(dmap, row, 16);
                if (row < nb) {
                    const f32x4* __restrict__ cw = (const f32x4*)(cls_W + j * E);
                    float a2 = cls_b[j];
                    #pragma unroll 8
                    for (int jj = 0; jj < 32; ++jj) {
                        const f32x4 y4 = *(const f32x4*)&Yl[row * (E + 4) + jj * 4];
                        const f32x4 w4 = cw[jj];
                        a2 += y4.x * w4.x + y4.y * w4.y + y4.z * w4.z + y4.w * w4.w;
                    }
                    out[(size_t)outb * OUT_DIM + j] = a2;
                }
                __syncthreads();                                  // Yl free for next tile
            }
        }
    }
}

extern "C" void kernel_launch(void* const* d_in, const int* in_sizes, int n_in,
                              void* d_out, int out_size, void* d_ws, size_t ws_size,
                              hipStream_t stream) {
    const int*   author_ids = (const int*)d_in[0];
    const int*   module_ids = (const int*)d_in[1];
    const float* embed      = (const float*)d_in[2];
    const float* W          = (const float*)d_in[3];
    const float* bias       = (const float*)d_in[4];
    const float* cls_W      = (const float*)d_in[5];
    const float* cls_b      = (const float*)d_in[6];
    float* out = (float*)d_out;
    int*   wsI = (int*)d_ws;

    void* args[] = {
        (void*)&module_ids, (void*)&author_ids, (void*)&embed, (void*)&W,
        (void*)&bias, (void*)&cls_W, (void*)&cls_b, (void*)&out, (void*)&wsI
    };
    hipLaunchCooperativeKernel((void*)fused_kernel, dim3(GRID), dim3(256),
                               args, 0, stream);
}

// Round 10
// 79.414 us; speedup vs baseline: 1.6289x; 1.6289x over previous
//
#include <hip/hip_runtime.h>

#define B_TOT   4096
#define NSTEPS  4
#define E       128
#define OUT_DIM 16
#define NMOD    64
#define KSPLIT  4
#define TILE    16
#define GRID    256
#define AGG     255

// ws int offsets (barrier region first, zeroed by memset node each replay):
#define SORTF_I    0                          // [4]
#define EPOCH_I    4                          // [3]
#define ARR_I      8                          // [3][256]
#define MSET_BYTES ((8 + 3 * GRID) * 4)       // 3104 B
#define CNT_I      1024                       // [4][64]
#define OFF_I      (CNT_I + 256)              // [4][64]
#define PERM_I     (CNT_I + 512)              // [4][4096]
#define RANK_I     (PERM_I + 4 * B_TOT)       // [4][4096]
#define PERMA0_I   (RANK_I + 4 * B_TOT)       // [4096]
#define XB_BYTE(i) ((size_t)(1 + (i)) << 20)  // XB0/1/2: [4096][64] u32, 1 MB each

typedef _Float16 f16;
using f16x8 = __attribute__((ext_vector_type(8))) f16;
using f32x4 = __attribute__((ext_vector_type(4))) float;
union HU  { f16 h; unsigned short u; };
union U4H { uint4 u4; f16x8 h8; };

#define AGENT __HIP_MEMORY_SCOPE_AGENT

__device__ __forceinline__ float tanh_fast(float x) {
    return 1.0f - 2.0f / (__expf(2.0f * x) + 1.0f);
}
__device__ __forceinline__ unsigned short f2h(float x) { HU v; v.h = (f16)x; return v.u; }
__device__ __forceinline__ void s_store(int* p, int v) {
    __hip_atomic_store(p, v, __ATOMIC_RELAXED, AGENT);
}
__device__ __forceinline__ void u_store(unsigned* p, unsigned v) {
    __hip_atomic_store(p, v, __ATOMIC_RELAXED, AGENT);
}
__device__ __forceinline__ int s_load(const int* p) {
    return __hip_atomic_load(p, __ATOMIC_RELAXED, AGENT);
}

__global__ __launch_bounds__(256, 1) void fused_kernel(
    const int* __restrict__ mids,
    const int* __restrict__ author_ids,
    const float* __restrict__ embed,
    const float* __restrict__ W,
    const float* __restrict__ bias,
    const float* __restrict__ cls_W,
    const float* __restrict__ cls_b,
    float* __restrict__ out,
    int* __restrict__ ws)
{
    const int bid = blockIdx.x;
    const int t   = threadIdx.x;
    const int w   = t >> 6;
    const int l   = t & 63;
    const int g   = l >> 4;
    const int r0  = l & 15;

    const int m  = bid & (NMOD - 1);
    const int k  = bid >> 6;
    const int c0 = 32 * w + r0;
    const int c1 = c0 + 16;

    __shared__ int s_h[NMOD];
    __shared__ int s_o[NMOD];
    __shared__ __align__(16) float Yl[TILE * (E + 4)];

    // ---- W[m] -> f16 hi/lo fragments in registers (loads overlap sort/spin) ----
    f16x8 BH0[4], BL0[4], BH1[4], BL1[4];
    {
        const float* __restrict__ wb = W + (size_t)m * E * E;
        #pragma unroll
        for (int ss = 0; ss < 4; ++ss) {
            const f32x4* __restrict__ p0 = (const f32x4*)(wb + c0 * E + ss * 32 + g * 8);
            const f32x4* __restrict__ p1 = (const f32x4*)(wb + c1 * E + ss * 32 + g * 8);
            const f32x4 a0 = p0[0], a1 = p0[1];
            const f32x4 d0 = p1[0], d1 = p1[1];
            const float x0[8] = {a0.x, a0.y, a0.z, a0.w, a1.x, a1.y, a1.z, a1.w};
            const float x1[8] = {d0.x, d0.y, d0.z, d0.w, d1.x, d1.y, d1.z, d1.w};
            #pragma unroll
            for (int j = 0; j < 8; ++j) {
                const f16 h0 = (f16)x0[j];
                const f16 h1 = (f16)x1[j];
                BH0[ss][j] = h0;  BL0[ss][j] = (f16)(x0[j] - (float)h0);
                BH1[ss][j] = h1;  BL1[ss][j] = (f16)(x1[j] - (float)h1);
            }
        }
    }
    const float b0 = bias[m * E + c0];
    const float b1 = bias[m * E + c1];

    // ================= blocks 0..3: counting sort (order-nondeterministic; per-row
    // results are position-independent, so output stays bit-identical) =============
    if (bid < NSTEPS) {
        const int s = bid;
        if (t < NMOD) s_h[t] = 0;
        __syncthreads();
        for (int b = t; b < B_TOT; b += 256)
            atomicAdd(&s_h[mids[b * NSTEPS + s]], 1);
        __syncthreads();
        if (t < NMOD) {                      // wave0 exclusive scan
            const int v = s_h[t];
            int inc = v;
            #pragma unroll
            for (int d = 1; d < NMOD; d <<= 1) {
                const int nv = __shfl_up(inc, d, 64);
                if (t >= d) inc += nv;
            }
            s_o[t] = inc - v;
        }
        __syncthreads();
        if (t < NMOD) {
            s_store(&ws[CNT_I + s * NMOD + t], s_h[t]);
            s_store(&ws[OFF_I + s * NMOD + t], s_o[t]);
            s_h[t] = s_o[t];                 // cursor
        }
        __syncthreads();
        int* __restrict__ perm = ws + PERM_I + s * B_TOT;
        int* __restrict__ rank = ws + RANK_I + s * B_TOT;
        for (int b = t; b < B_TOT; b += 256) {
            const int mm = mids[b * NSTEPS + s];
            const int p  = atomicAdd(&s_h[mm], 1);
            s_store(&perm[p], b);
            s_store(&rank[b], p);
            if (s == 0) s_store(&ws[PERMA0_I + p], author_ids[b]);
        }
        __syncthreads();                     // vmcnt drained: sc1 stores at MALL
        if (t == 0) s_store(&ws[SORTF_I + s], 1);
    }

    // ---- B0: wait for all 4 sorts ----
    if (t < NSTEPS)
        while (s_load(&ws[SORTF_I + t]) == 0)
            __builtin_amdgcn_s_sleep(2);
    __syncthreads();

    // ================= steps =================
    for (int s = 0; s < NSTEPS; ++s) {
        const int cnt = ws[CNT_I + s * NMOD + m];
        const int off = ws[OFF_I + s * NMOD + m];
        const int end = off + cnt;
        const int* __restrict__ permS = ws + PERM_I + s * B_TOT;
        const int* __restrict__ rankN = ws + RANK_I + ((s + 1) & 3) * B_TOT;  // used only s<3
        const unsigned* __restrict__ xbIn  = (s > 0) ? (const unsigned*)((char*)ws + XB_BYTE(s - 1)) : nullptr;
        unsigned*       __restrict__ xbOut = (s < 3) ? (unsigned*)((char*)ws + XB_BYTE(s))           : nullptr;

        for (int base = off + k * TILE; base < end; base += KSPLIT * TILE) {
            const int nb   = min(TILE, end - base);
            const bool rok = r0 < nb;
            const int rr   = base + (rok ? r0 : 0);

            const int ob   = permS[rr];
            const int dmap = (s < 3) ? rankN[ob] : ob;

            // ---- A fragments (row r0) ----
            f16x8 A[4];
            if (s == 0) {
                const f32x4* __restrict__ src =
                    (const f32x4*)(embed + (size_t)ws[PERMA0_I + rr] * E);
                #pragma unroll
                for (int ss = 0; ss < 4; ++ss) {
                    if (rok) {
                        const f32x4 v0 = src[ss * 8 + 2 * g];
                        const f32x4 v1 = src[ss * 8 + 2 * g + 1];
                        const float xf[8] = {v0.x, v0.y, v0.z, v0.w, v1.x, v1.y, v1.z, v1.w};
                        #pragma unroll
                        for (int j = 0; j < 8; ++j) A[ss][j] = (f16)xf[j];
                    } else {
                        #pragma unroll
                        for (int j = 0; j < 8; ++j) A[ss][j] = (f16)0.0f;
                    }
                }
            } else {
                const uint4* __restrict__ src = (const uint4*)xbIn + (size_t)rr * 16;
                #pragma unroll
                for (int ss = 0; ss < 4; ++ss) {
                    if (rok) {
                        U4H u; u.u4 = src[ss * 4 + g];
                        A[ss] = u.h8;
                    } else {
                        #pragma unroll
                        for (int j = 0; j < 8; ++j) A[ss][j] = (f16)0.0f;
                    }
                }
            }

            // ---- 16 MFMAs: acc = A * (Whi + Wlo) ----
            f32x4 acc0 = {0.f, 0.f, 0.f, 0.f};
            f32x4 acc1 = {0.f, 0.f, 0.f, 0.f};
            #pragma unroll
            for (int ss = 0; ss < 4; ++ss) {
                acc0 = __builtin_amdgcn_mfma_f32_16x16x32_f16(A[ss], BH0[ss], acc0, 0, 0, 0);
                acc1 = __builtin_amdgcn_mfma_f32_16x16x32_f16(A[ss], BH1[ss], acc1, 0, 0, 0);
                acc0 = __builtin_amdgcn_mfma_f32_16x16x32_f16(A[ss], BL0[ss], acc0, 0, 0, 0);
                acc1 = __builtin_amdgcn_mfma_f32_16x16x32_f16(A[ss], BL1[ss], acc1, 0, 0, 0);
            }

            // ---- epilogue ----
            if (s < 3) {
                // even/odd lane pairing -> u32 packed stores (sc1, straight to MALL)
                #pragma unroll
                for (int r = 0; r < 4; ++r) {
                    const int row = 4 * g + r;
                    const unsigned short v0 = f2h(tanh_fast(acc0[r] + b0));
                    const unsigned short v1 = f2h(tanh_fast(acc1[r] + b1));
                    const int dr = __shfl(dmap, row, 16);
                    const unsigned po0 = (unsigned)__shfl_xor((int)v0, 1) & 0xFFFFu;
                    const unsigned po1 = (unsigned)__shfl_xor((int)v1, 1) & 0xFFFFu;
                    if (!(l & 1) && row < nb) {
                        u_store(&xbOut[(size_t)dr * 64 + (c0 >> 1)], (unsigned)v0 | (po0 << 16));
                        u_store(&xbOut[(size_t)dr * 64 + (c1 >> 1)], (unsigned)v1 | (po1 << 16));
                    }
                }
            } else {
                #pragma unroll
                for (int r = 0; r < 4; ++r) {
                    const int row = 4 * g + r;
                    Yl[row * (E + 4) + c0] = acc0[r] + b0;
                    Yl[row * (E + 4) + c1] = acc1[r] + b1;
                }
                __syncthreads();
                const int row  = t >> 4, j = t & 15;
                const int outb = __shfl(dmap, row, 16);
                if (row < nb) {
                    const f32x4* __restrict__ cw = (const f32x4*)(cls_W + j * E);
                    float a2 = cls_b[j];
                    #pragma unroll 8
                    for (int jj = 0; jj < 32; ++jj) {
                        const f32x4 y4 = *(const f32x4*)&Yl[row * (E + 4) + jj * 4];
                        const f32x4 w4 = cw[jj];
                        a2 += y4.x * w4.x + y4.y * w4.y + y4.z * w4.z + y4.w * w4.w;
                    }
                    out[(size_t)outb * OUT_DIM + j] = a2;
                }
                __syncthreads();              // Yl free for next tile
            }
        }

        // ---- coarse barrier after steps 0..2 (no cache-maintenance ops) ----
        if (s < NSTEPS - 1) {
            __syncthreads();                  // vmcnt drained: all sc1 data at MALL
            if (t == 0) s_store(&ws[ARR_I + s * GRID + bid], 1);
            if (bid == AGG) {                 // aggregator: thread t polls slot t
                for (;;) {
                    const int v = s_load(&ws[ARR_I + s * GRID + t]);
                    if (__syncthreads_count(v != 0) == GRID) break;
                    __builtin_amdgcn_s_sleep(2);
                }
                if (t == 0) s_store(&ws[EPOCH_I + s], 1);
            }
            if (t == 0)
                while (s_load(&ws[EPOCH_I + s]) == 0)
                    __builtin_amdgcn_s_sleep(2);
            __syncthreads();
        }
    }
}

extern "C" void kernel_launch(void* const* d_in, const int* in_sizes, int n_in,
                              void* d_out, int out_size, void* d_ws, size_t ws_size,
                              hipStream_t stream) {
    const int*   author_ids = (const int*)d_in[0];
    const int*   module_ids = (const int*)d_in[1];
    const float* embed      = (const float*)d_in[2];
    const float* W          = (const float*)d_in[3];
    const float* bias       = (const float*)d_in[4];
    const float* cls_W      = (const float*)d_in[5];
    const float* cls_b      = (const float*)d_in[6];
    float* out = (float*)d_out;
    int*   wsI = (int*)d_ws;

    hipMemsetAsync(d_ws, 0, MSET_BYTES, stream);   // zero barrier flags each replay

    void* args[] = {
        (void*)&module_ids, (void*)&author_ids, (void*)&embed, (void*)&W,
        (void*)&bias, (void*)&cls_W, (void*)&cls_b, (void*)&out, (void*)&wsI
    };
    hipLaunchCooperativeKernel((void*)fused_kernel, dim3(GRID), dim3(256),
                               args, 0, stream);
}

// Round 12
// 76.899 us; speedup vs baseline: 1.6822x; 1.0327x over previous
//
#include <hip/hip_runtime.h>

#define B_TOT   4096
#define NSTEPS  4
#define E       128
#define OUT_DIM 16
#define NMOD    64
#define KSPLIT  4
#define TILE    16
#define GRID    256
#define BLOCK   512

// ws int offsets (barrier region first, zeroed by memset node each replay):
#define SORTF_I    0                          // [4]
#define GEN_I      16                         // + s*16, s=0..2
#define LEAF_I     64                         // + s*128 + leaf*16, 8 leaves
#define ROOT_I     448                        // + s*16
#define MSET_BYTES (512 * 4)                  // 2 KB
#define CNT_I      1024                       // [4][64]
#define OFF_I      (CNT_I + 256)              // [4][64]
#define PERM_I     (CNT_I + 512)              // [4][4096]
#define RANK_I     (PERM_I + 4 * B_TOT)       // [4][4096]
#define PERMA0_I   (RANK_I + 4 * B_TOT)       // [4096]
#define XB_BYTE(i) ((size_t)(1 + (i)) << 20)  // XB0/1/2: [4096][64] u32, 1 MB each

typedef _Float16 f16;
using f16x8 = __attribute__((ext_vector_type(8))) f16;
using f32x4 = __attribute__((ext_vector_type(4))) float;
union HU  { f16 h; unsigned short u; };
union U4H { uint4 u4; f16x8 h8; };

#define AGENT __HIP_MEMORY_SCOPE_AGENT

__device__ __forceinline__ float tanh_fast(float x) {
    return 1.0f - 2.0f / (__expf(2.0f * x) + 1.0f);
}
__device__ __forceinline__ unsigned short f2h(float x) { HU v; v.h = (f16)x; return v.u; }
__device__ __forceinline__ void s_store(int* p, int v) {
    __hip_atomic_store(p, v, __ATOMIC_RELAXED, AGENT);
}
__device__ __forceinline__ void u_store(unsigned* p, unsigned v) {
    __hip_atomic_store(p, v, __ATOMIC_RELAXED, AGENT);
}
__device__ __forceinline__ int s_load(const int* p) {
    return __hip_atomic_load(p, __ATOMIC_RELAXED, AGENT);
}
__device__ __forceinline__ int s_rmw(int* p) {
    return __hip_atomic_fetch_add(p, 1, __ATOMIC_RELAXED, AGENT);
}

__global__ __launch_bounds__(BLOCK, 2) void fused_kernel(
    const int* __restrict__ mids,
    const int* __restrict__ author_ids,
    const float* __restrict__ embed,
    const float* __restrict__ W,
    const float* __restrict__ bias,
    const float* __restrict__ cls_W,
    const float* __restrict__ cls_b,
    float* __restrict__ out,
    int* __restrict__ ws)
{
    const int bid = blockIdx.x;
    const int t   = threadIdx.x;          // 0..511
    const int w   = t >> 6;               // wave 0..7 -> column group
    const int l   = t & 63;
    const int g   = l >> 4;
    const int r0  = l & 15;

    const int m  = bid & (NMOD - 1);      // all 4 slices of module m on XCD m%8
    const int k  = bid >> 6;              // slice 0..3
    const int c0 = 16 * w + r0;           // this lane's output column

    __shared__ int s_h[NMOD];
    __shared__ int s_o[NMOD];
    __shared__ __align__(16) float Yl[TILE * (E + 4)];

    // ---- W[m] column c0 -> f16 hi/lo fragments in registers (32 VGPR) ----
    f16x8 BH[4], BL[4];
    {
        const float* __restrict__ wb = W + (size_t)m * E * E + c0 * E;
        #pragma unroll
        for (int ss = 0; ss < 4; ++ss) {
            const f32x4* __restrict__ p0 = (const f32x4*)(wb + ss * 32 + g * 8);
            const f32x4 a0 = p0[0], a1 = p0[1];
            const float x0[8] = {a0.x, a0.y, a0.z, a0.w, a1.x, a1.y, a1.z, a1.w};
            #pragma unroll
            for (int j = 0; j < 8; ++j) {
                const f16 h0 = (f16)x0[j];
                BH[ss][j] = h0;
                BL[ss][j] = (f16)(x0[j] - (float)h0);
            }
        }
    }
    const float b0 = bias[m * E + c0];

    // ================= blocks 0..3: counting sort (order-nondet; per-row results
    // position-independent -> outputs bit-identical across replays) ==============
    if (bid < NSTEPS) {
        const int s = bid;
        if (t < NMOD) s_h[t] = 0;
        __syncthreads();
        for (int b = t; b < B_TOT; b += BLOCK)
            atomicAdd(&s_h[mids[b * NSTEPS + s]], 1);
        __syncthreads();
        if (t < NMOD) {                      // wave0 exclusive scan
            const int v = s_h[t];
            int inc = v;
            #pragma unroll
            for (int d = 1; d < NMOD; d <<= 1) {
                const int nv = __shfl_up(inc, d, 64);
                if (t >= d) inc += nv;
            }
            s_o[t] = inc - v;
        }
        __syncthreads();
        if (t < NMOD) {
            s_store(&ws[CNT_I + s * NMOD + t], s_h[t]);
            s_store(&ws[OFF_I + s * NMOD + t], s_o[t]);
            s_h[t] = s_o[t];                 // cursor
        }
        __syncthreads();
        int* __restrict__ perm = ws + PERM_I + s * B_TOT;
        int* __restrict__ rank = ws + RANK_I + s * B_TOT;
        for (int b = t; b < B_TOT; b += BLOCK) {
            const int mm = mids[b * NSTEPS + s];
            const int p  = atomicAdd(&s_h[mm], 1);
            s_store(&perm[p], b);
            s_store(&rank[b], p);
            if (s == 0) s_store(&ws[PERMA0_I + p], author_ids[b]);
        }
        __syncthreads();                     // vmcnt drained: sc1 stores at MALL
        if (t == 0) s_store(&ws[SORTF_I + s], 1);
    }

    // ---- wait for all 4 sorts ----
    if (t < NSTEPS)
        while (s_load(&ws[SORTF_I + t]) == 0)
            __builtin_amdgcn_s_sleep(1);
    __syncthreads();

    // ================= steps =================
    for (int s = 0; s < NSTEPS; ++s) {
        const int cnt = ws[CNT_I + s * NMOD + m];
        const int off = ws[OFF_I + s * NMOD + m];
        const int end = off + cnt;
        const int* __restrict__ permS = ws + PERM_I + s * B_TOT;
        const int* __restrict__ rankN = ws + RANK_I + ((s + 1) & 3) * B_TOT;  // used only s<3
        const unsigned* __restrict__ xbIn  = (s > 0) ? (const unsigned*)((char*)ws + XB_BYTE(s - 1)) : nullptr;
        unsigned*       __restrict__ xbOut = (s < 3) ? (unsigned*)((char*)ws + XB_BYTE(s))           : nullptr;

        for (int base = off + k * TILE; base < end; base += KSPLIT * TILE) {
            const int nb   = min(TILE, end - base);
            const bool rok = r0 < nb;
            const int rr   = base + (rok ? r0 : 0);

            const int ob   = permS[rr];
            const int dmap = (s < 3) ? rankN[ob] : ob;

            // ---- A fragments (row r0; same rows in every wave, L1-shared) ----
            f16x8 A[4];
            if (s == 0) {
                const f32x4* __restrict__ src =
                    (const f32x4*)(embed + (size_t)ws[PERMA0_I + rr] * E);
                #pragma unroll
                for (int ss = 0; ss < 4; ++ss) {
                    if (rok) {
                        const f32x4 v0 = src[ss * 8 + 2 * g];
                        const f32x4 v1 = src[ss * 8 + 2 * g + 1];
                        const float xf[8] = {v0.x, v0.y, v0.z, v0.w, v1.x, v1.y, v1.z, v1.w};
                        #pragma unroll
                        for (int j = 0; j < 8; ++j) A[ss][j] = (f16)xf[j];
                    } else {
                        #pragma unroll
                        for (int j = 0; j < 8; ++j) A[ss][j] = (f16)0.0f;
                    }
                }
            } else {
                const uint4* __restrict__ src = (const uint4*)xbIn + (size_t)rr * 16;
                #pragma unroll
                for (int ss = 0; ss < 4; ++ss) {
                    if (rok) {
                        U4H u; u.u4 = src[ss * 4 + g];
                        A[ss] = u.h8;
                    } else {
                        #pragma unroll
                        for (int j = 0; j < 8; ++j) A[ss][j] = (f16)0.0f;
                    }
                }
            }

            // ---- 8 MFMAs: acc = A * (Whi + Wlo) ----
            f32x4 acc = {0.f, 0.f, 0.f, 0.f};
            #pragma unroll
            for (int ss = 0; ss < 4; ++ss) {
                acc = __builtin_amdgcn_mfma_f32_16x16x32_f16(A[ss], BH[ss], acc, 0, 0, 0);
                acc = __builtin_amdgcn_mfma_f32_16x16x32_f16(A[ss], BL[ss], acc, 0, 0, 0);
            }

            // ---- epilogue: D row = 4g + r, col c0 ----
            if (s < 3) {
                // even/odd lane pairing -> packed u32 sc1 stores (straight to MALL)
                #pragma unroll
                for (int r = 0; r < 4; ++r) {
                    const int row = 4 * g + r;
                    const unsigned short v0 = f2h(tanh_fast(acc[r] + b0));
                    const int dr = __shfl(dmap, row, 16);
                    const unsigned po0 = (unsigned)__shfl_xor((int)v0, 1) & 0xFFFFu;
                    if (!(l & 1) && row < nb)
                        u_store(&xbOut[(size_t)dr * 64 + (c0 >> 1)], (unsigned)v0 | (po0 << 16));
                }
            } else {
                #pragma unroll
                for (int r = 0; r < 4; ++r) {
                    const int row = 4 * g + r;
                    Yl[row * (E + 4) + c0] = acc[r] + b0;
                }
                __syncthreads();
                if (t < 256) {
                    const int row  = t >> 4, j = t & 15;
                    const int outb = __shfl(dmap, row, 16);
                    if (row < nb) {
                        const f32x4* __restrict__ cw = (const f32x4*)(cls_W + j * E);
                        float a2 = cls_b[j];
                        #pragma unroll 8
                        for (int jj = 0; jj < 32; ++jj) {
                            const f32x4 y4 = *(const f32x4*)&Yl[row * (E + 4) + jj * 4];
                            const f32x4 w4 = cw[jj];
                            a2 += y4.x * w4.x + y4.y * w4.y + y4.z * w4.z + y4.w * w4.w;
                        }
                        out[(size_t)outb * OUT_DIM + j] = a2;
                    }
                }
                __syncthreads();              // Yl free for next tile
            }
        }

        // ---- tree barrier after steps 0..2 (no cache-maintenance ops) ----
        if (s < NSTEPS - 1) {
            __syncthreads();                  // vmcnt drained: sc1 data at MALL
            if (t == 0) {
                if (s_rmw(&ws[LEAF_I + s * 128 + (bid & 7) * 16]) == (GRID / 8) - 1) {
                    if (s_rmw(&ws[ROOT_I + s * 16]) == 7)
                        s_store(&ws[GEN_I + s * 16], 1);
                }
                while (s_load(&ws[GEN_I + s * 16]) == 0)
                    __builtin_amdgcn_s_sleep(1);
            }
            __syncthreads();
        }
    }
}

extern "C" void kernel_launch(void* const* d_in, const int* in_sizes, int n_in,
                              void* d_out, int out_size, void* d_ws, size_t ws_size,
                              hipStream_t stream) {
    const int*   author_ids = (const int*)d_in[0];
    const int*   module_ids = (const int*)d_in[1];
    const float* embed      = (const float*)d_in[2];
    const float* W          = (const float*)d_in[3];
    const float* bias       = (const float*)d_in[4];
    const float* cls_W      = (const float*)d_in[5];
    const float* cls_b      = (const float*)d_in[6];
    float* out = (float*)d_out;
    int*   wsI = (int*)d_ws;

    hipMemsetAsync(d_ws, 0, MSET_BYTES, stream);   // zero barrier state each replay

    void* args[] = {
        (void*)&module_ids, (void*)&author_ids, (void*)&embed, (void*)&W,
        (void*)&bias, (void*)&cls_W, (void*)&cls_b, (void*)&out, (void*)&wsI
    };
    hipLaunchCooperativeKernel((void*)fused_kernel, dim3(GRID), dim3(BLOCK),
                               args, 0, stream);
}